// Round 5
// baseline (322.846 us; speedup 1.0000x reference)
//
#include <hip/hip_runtime.h>
#include <hip/hip_bf16.h>
#include <cstdint>
#include <cstddef>

#define T_TOTAL 32768
#define F_IN    73
#define H_FNN   512
#define D_FNN   256
#define H_RNN   128
#define G4      512      // 4*H_RNN
#define SEG     128      // output steps per segment
#define BURN    128      // burn-in steps
#define NSEG    (T_TOTAL / SEG)   // 256 blocks = 1 per CU
#define OUT_COLS 384
#define KP1     96       // layer-1 K padded (73 -> 96 = 3 x 32)

typedef short bf16x8 __attribute__((ext_vector_type(8)));
typedef float f32x4  __attribute__((ext_vector_type(4)));

// ---------------- helpers ----------------

// sum across 8-lane group {8a..8a+7}: xor1,xor2 via DPP quad_perm, xor4 via ds_swizzle
__device__ __forceinline__ float sum8(float x) {
    int xi = __float_as_int(x);
    x += __int_as_float(__builtin_amdgcn_mov_dpp(xi, 0xB1, 0xF, 0xF, true)); // xor1 [1,0,3,2]
    xi = __float_as_int(x);
    x += __int_as_float(__builtin_amdgcn_mov_dpp(xi, 0x4E, 0xF, 0xF, true)); // xor2 [2,3,0,1]
    xi = __float_as_int(x);
    x += __int_as_float(__builtin_amdgcn_ds_swizzle(xi, 0x101F));            // xor4 (BitMode)
    return x;
}

__device__ __forceinline__ float fast_sigmoid(float x) {
    float e = __expf(-x);
    return __builtin_amdgcn_rcpf(1.f + e);
}
__device__ __forceinline__ float fast_tanh(float x) {
    float e = __expf(2.f * x);
    return 1.f - 2.f * __builtin_amdgcn_rcpf(e + 1.f);
}

// ---------------- cast kernels (prep bf16 MFMA operands) ----------------

__global__ void cast_features(const float* __restrict__ f, __hip_bfloat16* __restrict__ A) {
    int idx = blockIdx.x * 256 + threadIdx.x;       // over T_TOTAL*KP1
    int r = idx / KP1, c = idx % KP1;
    A[idx] = __float2bfloat16(c < F_IN ? f[(size_t)r * F_IN + c] : 0.f);
}
__global__ void cast_w1(const float* __restrict__ W1, __hip_bfloat16* __restrict__ W1b) {
    int idx = blockIdx.x * 256 + threadIdx.x;       // over H_FNN*KP1
    int n = idx / KP1, k = idx % KP1;
    W1b[idx] = __float2bfloat16(k < F_IN ? W1[(size_t)n * F_IN + k] : 0.f);
}
__global__ void cast_w2(const float* __restrict__ W2, __hip_bfloat16* __restrict__ W2b) {
    int idx = blockIdx.x * 256 + threadIdx.x;       // over D_FNN*H_FNN
    W2b[idx] = __float2bfloat16(W2[idx]);           // W2 is already [n=256][k=512]
}

// ---------------- kernel 2: x_gates = x[:,D_SET] @ W_ih.T + b_ih + b_hh ----------------

__global__ __launch_bounds__(512) void xgates_kernel(
    const float* __restrict__ features,
    const float* __restrict__ W_ih,
    const float* __restrict__ b_ih,
    const float* __restrict__ b_hh,
    float* __restrict__ xg)
{
    const int tid = threadIdx.x;
    const int t0  = blockIdx.x * 32;
    __shared__ float xt[32][28];

    for (int idx = tid; idx < 32 * 28; idx += 512) {
        int r = idx / 28, c = idx % 28;
        float v = 0.f;
        if (c < 25) {
            int col = (c == 0) ? 0 : (48 + c);        // D_SET = [0, 49..72]
            v = features[(size_t)(t0 + r) * F_IN + col];
        }
        xt[r][c] = v;
    }
    __syncthreads();

    const int j = tid;
    float w[28];
#pragma unroll
    for (int k = 0; k < 25; ++k) w[k] = W_ih[j * 25 + k];
    w[25] = w[26] = w[27] = 0.f;
    const float bias = b_ih[j] + b_hh[j];

    float acc[32];
#pragma unroll
    for (int r = 0; r < 32; ++r) acc[r] = bias;
#pragma unroll
    for (int k4 = 0; k4 < 7; ++k4) {
#pragma unroll
        for (int r = 0; r < 32; ++r) {
            float4 a = *reinterpret_cast<const float4*>(&xt[r][k4 * 4]);
            acc[r] += a.x * w[4*k4] + a.y * w[4*k4+1] + a.z * w[4*k4+2] + a.w * w[4*k4+3];
        }
    }
#pragma unroll
    for (int r = 0; r < 32; ++r)
        xg[(size_t)(t0 + r) * G4 + j] = acc[r];
}

// ---------------- kernel 3: FNN via bf16 MFMA (unchanged from round 4) ----------------

__global__ __launch_bounds__(512, 2) void fnn_mfma(
    const __hip_bfloat16* __restrict__ Abf,   // [T][96]
    const __hip_bfloat16* __restrict__ W1bf,  // [512][96]
    const float* __restrict__ b1,
    const __hip_bfloat16* __restrict__ W2bf,  // [256][512]
    const float* __restrict__ b2,
    float* __restrict__ out)
{
    __shared__ __attribute__((aligned(16))) __hip_bfloat16 c1[64][520];
    const int tid  = threadIdx.x;
    const int wid  = tid >> 6;
    const int lane = tid & 63;
    const int lr   = lane & 15;
    const int lg   = lane >> 4;
    const int wm   = wid >> 2;
    const int wn   = wid & 3;
    const int m0   = blockIdx.x * 64;

    f32x4 acc1[2][8];
#pragma unroll
    for (int i = 0; i < 2; ++i)
#pragma unroll
        for (int j = 0; j < 8; ++j)
            acc1[i][j] = (f32x4){0.f, 0.f, 0.f, 0.f};

#pragma unroll
    for (int ks = 0; ks < 3; ++ks) {
        const int k0 = ks * 32 + lg * 8;
        bf16x8 a[2], b[8];
#pragma unroll
        for (int mf = 0; mf < 2; ++mf) {
            const int row = m0 + wm * 32 + mf * 16 + lr;
            a[mf] = *reinterpret_cast<const bf16x8*>(Abf + (size_t)row * KP1 + k0);
        }
#pragma unroll
        for (int nf = 0; nf < 8; ++nf) {
            const int col = wn * 128 + nf * 16 + lr;
            b[nf] = *reinterpret_cast<const bf16x8*>(W1bf + (size_t)col * KP1 + k0);
        }
#pragma unroll
        for (int mf = 0; mf < 2; ++mf)
#pragma unroll
            for (int nf = 0; nf < 8; ++nf)
                acc1[mf][nf] = __builtin_amdgcn_mfma_f32_16x16x32_bf16(
                    a[mf], b[nf], acc1[mf][nf], 0, 0, 0);
    }

#pragma unroll
    for (int nf = 0; nf < 8; ++nf) {
        const int col = wn * 128 + nf * 16 + lr;
        const float bv = b1[col];
#pragma unroll
        for (int mf = 0; mf < 2; ++mf) {
            const int rowb = wm * 32 + mf * 16 + lg * 4;
#pragma unroll
            for (int r = 0; r < 4; ++r) {
                float v = fmaxf(acc1[mf][nf][r] + bv, 0.f);
                c1[rowb + r][col] = __float2bfloat16(v);
            }
        }
    }
    __syncthreads();

    f32x4 acc2[2][4];
#pragma unroll
    for (int i = 0; i < 2; ++i)
#pragma unroll
        for (int j = 0; j < 4; ++j)
            acc2[i][j] = (f32x4){0.f, 0.f, 0.f, 0.f};

#pragma unroll
    for (int ks = 0; ks < 16; ++ks) {
        const int k0 = ks * 32 + lg * 8;
        bf16x8 a[2], b[4];
#pragma unroll
        for (int mf = 0; mf < 2; ++mf) {
            const int row = wm * 32 + mf * 16 + lr;
            a[mf] = *reinterpret_cast<const bf16x8*>(&c1[row][k0]);
        }
#pragma unroll
        for (int nf = 0; nf < 4; ++nf) {
            const int col = wn * 64 + nf * 16 + lr;
            b[nf] = *reinterpret_cast<const bf16x8*>(W2bf + (size_t)col * H_FNN + k0);
        }
#pragma unroll
        for (int mf = 0; mf < 2; ++mf)
#pragma unroll
            for (int nf = 0; nf < 4; ++nf)
                acc2[mf][nf] = __builtin_amdgcn_mfma_f32_16x16x32_bf16(
                    a[mf], b[nf], acc2[mf][nf], 0, 0, 0);
    }

#pragma unroll
    for (int nf = 0; nf < 4; ++nf) {
        const int col = wn * 64 + nf * 16 + lr;
        const float bv = b2[col];
#pragma unroll
        for (int mf = 0; mf < 2; ++mf) {
#pragma unroll
            for (int r = 0; r < 4; ++r) {
                const int row = m0 + wm * 32 + mf * 16 + lg * 4 + r;
                float v = fmaxf(acc2[mf][nf][r] + bv, 0.f);
                out[(size_t)row * OUT_COLS + col] = v;
                out[((size_t)T_TOTAL + row) * OUT_COLS + col] = v;
            }
        }
    }
}

// ---------------- kernel 4: segmented LSTM scan, 1024-thread variant ----------------
// 256 blocks (1/CU) x 1024 threads (16 waves, 4/SIMD). Thread (m = tid>>3, o = tid&7):
// owns all 4 gates of row m over k-slice [16o, 16o+16) -> only 64 weights/thread
// (rounds 2-4: 128 weights/thread lost the arch-VGPR budget fight -> AGPR
// round-trips at ~2 cy/weight/step; 64+~45 fits under a 128-VGPR budget).
// 8-lane butterfly reduce (2 DPP stages + 1 ds_swizzle xor4). h in LDS as 8
// k-slices at stride 20 floats -> ds_read_b128 bank-starts {0,20,8,28,16,4,24,12}
// = conflict-free. No asm pins (they caused the AGPR shuffling).

__global__ __attribute__((amdgpu_flat_work_group_size(1024, 1024),
                          amdgpu_waves_per_eu(4, 4)))
void lstm_kernel(
    const float* __restrict__ xg,
    const float* __restrict__ W_hh,
    float* __restrict__ out)
{
    const int tid = threadIdx.x;
    const int m   = tid >> 3;          // 0..127 gate row
    const int o   = tid & 7;           // k-slice index
    const int t_out = blockIdx.x * SEG;
    const int t0  = (t_out > BURN) ? (t_out - BURN) : 0;
    const int t1  = t_out + SEG;

    // weights: wv[g][kk] = W_hh[g*128+m][16*o+kk]  (64 floats)
    float wv[4][16];
#pragma unroll
    for (int g = 0; g < 4; ++g) {
        const float4* Wp = reinterpret_cast<const float4*>(
            W_hh + (size_t)(g * H_RNN + m) * H_RNN + o * 16);
#pragma unroll
        for (int i4 = 0; i4 < 4; ++i4) {
            float4 v = Wp[i4];
            wv[g][4*i4+0] = v.x; wv[g][4*i4+1] = v.y;
            wv[g][4*i4+2] = v.z; wv[g][4*i4+3] = v.w;
        }
    }

    __shared__ float hbuf[2][160];     // 8 slices x 20 floats (pad 16->20)
    if (tid < 160) hbuf[0][tid] = 0.f;
    float c = 0.f;
    __syncthreads();

    int p = 0;

    // xg prefetch for first step
    float x0, x1, x2, x3;
    {
        const float* xp = xg + (size_t)t0 * G4 + m;
        x0 = xp[0]; x1 = xp[128]; x2 = xp[256]; x3 = xp[384];
    }

    for (int t = t0; t < t1; ++t) {
        float nx0 = 0.f, nx1 = 0.f, nx2 = 0.f, nx3 = 0.f;
        if (t + 1 < t1) {
            const float* xp = xg + (size_t)(t + 1) * G4 + m;
            nx0 = xp[0]; nx1 = xp[128]; nx2 = xp[256]; nx3 = xp[384];
        }

        // read this thread's k-slice of h (16 floats, conflict-free b128s)
        const float4* h4 = reinterpret_cast<const float4*>(&hbuf[p][o * 20]);
        float a0i = 0.f, a1i = 0.f, a0f = 0.f, a1f = 0.f;
        float a0g = 0.f, a1g = 0.f, a0o = 0.f, a1o = 0.f;
#pragma unroll
        for (int i4 = 0; i4 < 4; ++i4) {
            float4 hv = h4[i4];
            if (i4 & 1) {
                a1i += hv.x*wv[0][4*i4] + hv.y*wv[0][4*i4+1] + hv.z*wv[0][4*i4+2] + hv.w*wv[0][4*i4+3];
                a1f += hv.x*wv[1][4*i4] + hv.y*wv[1][4*i4+1] + hv.z*wv[1][4*i4+2] + hv.w*wv[1][4*i4+3];
                a1g += hv.x*wv[2][4*i4] + hv.y*wv[2][4*i4+1] + hv.z*wv[2][4*i4+2] + hv.w*wv[2][4*i4+3];
                a1o += hv.x*wv[3][4*i4] + hv.y*wv[3][4*i4+1] + hv.z*wv[3][4*i4+2] + hv.w*wv[3][4*i4+3];
            } else {
                a0i += hv.x*wv[0][4*i4] + hv.y*wv[0][4*i4+1] + hv.z*wv[0][4*i4+2] + hv.w*wv[0][4*i4+3];
                a0f += hv.x*wv[1][4*i4] + hv.y*wv[1][4*i4+1] + hv.z*wv[1][4*i4+2] + hv.w*wv[1][4*i4+3];
                a0g += hv.x*wv[2][4*i4] + hv.y*wv[2][4*i4+1] + hv.z*wv[2][4*i4+2] + hv.w*wv[2][4*i4+3];
                a0o += hv.x*wv[3][4*i4] + hv.y*wv[3][4*i4+1] + hv.z*wv[3][4*i4+2] + hv.w*wv[3][4*i4+3];
            }
        }
        float ai = sum8(a0i + a1i) + x0;
        float af = sum8(a0f + a1f) + x1;
        float ag = sum8(a0g + a1g) + x2;
        float ao = sum8(a0o + a1o) + x3;

        float I = fast_sigmoid(ai);
        float F = fast_sigmoid(af);
        float G = fast_tanh(ag);
        float O = fast_sigmoid(ao);
        c = F * c + I * G;                 // redundant in all 8 lanes (identical)
        float h = O * fast_tanh(c);

        if (o == 0) {
            hbuf[p ^ 1][(m >> 4) * 20 + (m & 15)] = h;
            if (t >= t_out) {
                float r = fmaxf(h, 0.f);
                out[(size_t)t * OUT_COLS + 256 + m] = r;
                out[(size_t)(T_TOTAL + t) * OUT_COLS + 256 + m] = r;
            }
        }
        __syncthreads();                   // single barrier/step (double-buffered h)
        p ^= 1;
        x0 = nx0; x1 = nx1; x2 = nx2; x3 = nx3;
    }
}

// ---------------- host ----------------

extern "C" void kernel_launch(void* const* d_in, const int* in_sizes, int n_in,
                              void* d_out, int out_size, void* d_ws, size_t ws_size,
                              hipStream_t stream) {
    const float* features = (const float*)d_in[0];
    const float* W1   = (const float*)d_in[1];
    const float* b1   = (const float*)d_in[2];
    const float* W2   = (const float*)d_in[3];
    const float* b2   = (const float*)d_in[4];
    const float* W_ih = (const float*)d_in[5];
    const float* b_ih = (const float*)d_in[6];
    const float* W_hh = (const float*)d_in[7];
    const float* b_hh = (const float*)d_in[8];
    float* out = (float*)d_out;

    char* ws = (char*)d_ws;
    float*          xg   = (float*)ws;
    size_t off = (size_t)T_TOTAL * G4 * 4;
    __hip_bfloat16* Abf  = (__hip_bfloat16*)(ws + off); off += (size_t)T_TOTAL * KP1 * 2;
    __hip_bfloat16* W1bf = (__hip_bfloat16*)(ws + off); off += (size_t)H_FNN * KP1 * 2;
    __hip_bfloat16* W2bf = (__hip_bfloat16*)(ws + off);

    hipLaunchKernelGGL(cast_features, dim3(T_TOTAL * KP1 / 256), dim3(256), 0, stream, features, Abf);
    hipLaunchKernelGGL(cast_w1,       dim3(H_FNN * KP1 / 256),  dim3(256), 0, stream, W1, W1bf);
    hipLaunchKernelGGL(cast_w2,       dim3(D_FNN * H_FNN / 256), dim3(256), 0, stream, W2, W2bf);
    hipLaunchKernelGGL(xgates_kernel, dim3(T_TOTAL / 32), dim3(512), 0, stream,
                       features, W_ih, b_ih, b_hh, xg);
    hipLaunchKernelGGL(fnn_mfma,      dim3(T_TOTAL / 64), dim3(512), 0, stream,
                       Abf, W1bf, b1, W2bf, b2, out);
    hipLaunchKernelGGL(lstm_kernel,   dim3(NSEG), dim3(1024), 0, stream, xg, W_hh, out);
}

// Round 6
// 206.910 us; speedup vs baseline: 1.5603x; 1.5603x over previous
//
#include <hip/hip_runtime.h>
#include <hip/hip_bf16.h>
#include <cstdint>
#include <cstddef>

#define T_TOTAL 32768
#define F_IN    73
#define H_FNN   512
#define D_FNN   256
#define H_RNN   128
#define G4      512
#define SEG     32        // output steps per segment
#define BURN    128       // burn-in steps (validated rounds 3-5)
#define NSEG    (T_TOTAL / SEG)    // 1024 segments
#define BPB     4         // segments per block (MFMA batch rows)
#define NBLK    (NSEG / BPB)       // 256 blocks = 1/CU
#define STEPS   (SEG + BURN)       // 160
#define OUT_COLS 384
#define KP1     96

typedef short bf16x8 __attribute__((ext_vector_type(8)));
typedef float f32x4  __attribute__((ext_vector_type(4)));

// ---------------- helpers ----------------

__device__ __forceinline__ float fast_sigmoid(float x) {
    float e = __expf(-x);
    return __builtin_amdgcn_rcpf(1.f + e);
}
__device__ __forceinline__ float fast_tanh(float x) {
    float e = __expf(2.f * x);
    return 1.f - 2.f * __builtin_amdgcn_rcpf(e + 1.f);
}

// ---------------- cast kernels ----------------

__global__ void cast_features(const float* __restrict__ f, __hip_bfloat16* __restrict__ A) {
    int idx = blockIdx.x * 256 + threadIdx.x;
    int r = idx / KP1, c = idx % KP1;
    A[idx] = __float2bfloat16(c < F_IN ? f[(size_t)r * F_IN + c] : 0.f);
}
__global__ void cast_w1(const float* __restrict__ W1, __hip_bfloat16* __restrict__ W1b) {
    int idx = blockIdx.x * 256 + threadIdx.x;
    int n = idx / KP1, k = idx % KP1;
    W1b[idx] = __float2bfloat16(k < F_IN ? W1[(size_t)n * F_IN + k] : 0.f);
}
__global__ void cast_w2(const float* __restrict__ W2, __hip_bfloat16* __restrict__ W2b) {
    int idx = blockIdx.x * 256 + threadIdx.x;
    W2b[idx] = __float2bfloat16(W2[idx]);
}
// W_hh rows reordered to gate-interleave: row n' = (m<<2)|g  <->  orig row g*128+m
__global__ void cast_whh(const float* __restrict__ W_hh, __hip_bfloat16* __restrict__ Whh2) {
    int idx = blockIdx.x * 256 + threadIdx.x;     // over 512*128
    int np = idx >> 7, k = idx & 127;
    int m = np >> 2, g = np & 3;
    Whh2[idx] = __float2bfloat16(W_hh[(size_t)(g * H_RNN + m) * H_RNN + k]);
}

// ---------------- x_gates (permuted bf16 output) ----------------

__global__ __launch_bounds__(512) void xgates_kernel(
    const float* __restrict__ features,
    const float* __restrict__ W_ih,
    const float* __restrict__ b_ih,
    const float* __restrict__ b_hh,
    __hip_bfloat16* __restrict__ xg2)     // [T][512], col n' = (m<<2)|g
{
    const int tid = threadIdx.x;
    const int t0  = blockIdx.x * 32;
    __shared__ float xt[32][28];

    for (int idx = tid; idx < 32 * 28; idx += 512) {
        int r = idx / 28, c = idx % 28;
        float v = 0.f;
        if (c < 25) {
            int col = (c == 0) ? 0 : (48 + c);        // D_SET = [0, 49..72]
            v = features[(size_t)(t0 + r) * F_IN + col];
        }
        xt[r][c] = v;
    }
    __syncthreads();

    const int j = tid;                        // orig gate row: g = j>>7, m = j&127
    float w[28];
#pragma unroll
    for (int k = 0; k < 25; ++k) w[k] = W_ih[j * 25 + k];
    w[25] = w[26] = w[27] = 0.f;
    const float bias = b_ih[j] + b_hh[j];

    float acc[32];
#pragma unroll
    for (int r = 0; r < 32; ++r) acc[r] = bias;
#pragma unroll
    for (int k4 = 0; k4 < 7; ++k4) {
#pragma unroll
        for (int r = 0; r < 32; ++r) {
            float4 a = *reinterpret_cast<const float4*>(&xt[r][k4 * 4]);
            acc[r] += a.x * w[4*k4] + a.y * w[4*k4+1] + a.z * w[4*k4+2] + a.w * w[4*k4+3];
        }
    }
    const int np = ((j & 127) << 2) | (j >> 7);
#pragma unroll
    for (int r = 0; r < 32; ++r)
        xg2[(size_t)(t0 + r) * G4 + np] = __float2bfloat16(acc[r]);
}

// ---------------- FNN via bf16 MFMA (unchanged, validated round 4) ----------------

__global__ __launch_bounds__(512, 2) void fnn_mfma(
    const __hip_bfloat16* __restrict__ Abf,
    const __hip_bfloat16* __restrict__ W1bf,
    const float* __restrict__ b1,
    const __hip_bfloat16* __restrict__ W2bf,
    const float* __restrict__ b2,
    float* __restrict__ out)
{
    __shared__ __attribute__((aligned(16))) __hip_bfloat16 c1[64][520];
    const int tid  = threadIdx.x;
    const int wid  = tid >> 6;
    const int lane = tid & 63;
    const int lr   = lane & 15;
    const int lg   = lane >> 4;
    const int wm   = wid >> 2;
    const int wn   = wid & 3;
    const int m0   = blockIdx.x * 64;

    f32x4 acc1[2][8];
#pragma unroll
    for (int i = 0; i < 2; ++i)
#pragma unroll
        for (int j = 0; j < 8; ++j)
            acc1[i][j] = (f32x4){0.f, 0.f, 0.f, 0.f};

#pragma unroll
    for (int ks = 0; ks < 3; ++ks) {
        const int k0 = ks * 32 + lg * 8;
        bf16x8 a[2], b[8];
#pragma unroll
        for (int mf = 0; mf < 2; ++mf) {
            const int row = m0 + wm * 32 + mf * 16 + lr;
            a[mf] = *reinterpret_cast<const bf16x8*>(Abf + (size_t)row * KP1 + k0);
        }
#pragma unroll
        for (int nf = 0; nf < 8; ++nf) {
            const int col = wn * 128 + nf * 16 + lr;
            b[nf] = *reinterpret_cast<const bf16x8*>(W1bf + (size_t)col * KP1 + k0);
        }
#pragma unroll
        for (int mf = 0; mf < 2; ++mf)
#pragma unroll
            for (int nf = 0; nf < 8; ++nf)
                acc1[mf][nf] = __builtin_amdgcn_mfma_f32_16x16x32_bf16(
                    a[mf], b[nf], acc1[mf][nf], 0, 0, 0);
    }

#pragma unroll
    for (int nf = 0; nf < 8; ++nf) {
        const int col = wn * 128 + nf * 16 + lr;
        const float bv = b1[col];
#pragma unroll
        for (int mf = 0; mf < 2; ++mf) {
            const int rowb = wm * 32 + mf * 16 + lg * 4;
#pragma unroll
            for (int r = 0; r < 4; ++r) {
                float v = fmaxf(acc1[mf][nf][r] + bv, 0.f);
                c1[rowb + r][col] = __float2bfloat16(v);
            }
        }
    }
    __syncthreads();

    f32x4 acc2[2][4];
#pragma unroll
    for (int i = 0; i < 2; ++i)
#pragma unroll
        for (int j = 0; j < 4; ++j)
            acc2[i][j] = (f32x4){0.f, 0.f, 0.f, 0.f};

#pragma unroll
    for (int ks = 0; ks < 16; ++ks) {
        const int k0 = ks * 32 + lg * 8;
        bf16x8 a[2], b[4];
#pragma unroll
        for (int mf = 0; mf < 2; ++mf) {
            const int row = wm * 32 + mf * 16 + lr;
            a[mf] = *reinterpret_cast<const bf16x8*>(&c1[row][k0]);
        }
#pragma unroll
        for (int nf = 0; nf < 4; ++nf) {
            const int col = wn * 64 + nf * 16 + lr;
            b[nf] = *reinterpret_cast<const bf16x8*>(W2bf + (size_t)col * H_FNN + k0);
        }
#pragma unroll
        for (int mf = 0; mf < 2; ++mf)
#pragma unroll
            for (int nf = 0; nf < 4; ++nf)
                acc2[mf][nf] = __builtin_amdgcn_mfma_f32_16x16x32_bf16(
                    a[mf], b[nf], acc2[mf][nf], 0, 0, 0);
    }

#pragma unroll
    for (int nf = 0; nf < 4; ++nf) {
        const int col = wn * 64 + nf * 16 + lr;
        const float bv = b2[col];
#pragma unroll
        for (int mf = 0; mf < 2; ++mf) {
#pragma unroll
            for (int r = 0; r < 4; ++r) {
                const int row = m0 + wm * 32 + mf * 16 + lg * 4 + r;
                float v = fmaxf(acc2[mf][nf][r] + bv, 0.f);
                out[(size_t)row * OUT_COLS + col] = v;
                out[((size_t)T_TOTAL + row) * OUT_COLS + col] = v;
            }
        }
    }
}

// ---------------- batched-MFMA LSTM ----------------
// 256 blocks x 512 threads (8 waves, 2/SIMD). Block = 4 segments stepped together.
// Per step: gates[16][512] = H[16][128] @ Whh2^T via 16x16x32 bf16 MFMA (rows 4..15
// zero). Weights are MFMA B-operands -> AGPR parking is FREE (vs rounds 2-5 where
// VALU weights lost the arch-VGPR fight 3x). Gate columns interleaved n'=(m<<2)|g
// so the update lane reads its 4 gates as ONE ds_read_b128 and xg as one b64.
// Update: 1 (s,m) pair per lane -> zero transcendental redundancy.

__global__ __attribute__((amdgpu_flat_work_group_size(512, 512),
                          amdgpu_waves_per_eu(2, 2)))
void lstm_mfma(
    const __hip_bfloat16* __restrict__ xg2,   // [T][512] permuted
    const __hip_bfloat16* __restrict__ Whh2,  // [512][128] row n'
    float* __restrict__ out)
{
    const int tid = threadIdx.x;
    const int l   = tid & 63;
    const int w   = tid >> 6;        // wave 0..7
    const int lr  = l & 15;
    const int lg  = l >> 4;
    const int s_u = tid >> 7;        // update: segment row 0..3
    const int m_u = tid & 127;       // update: hidden index 0..127

    // A-operand staging: hA[buf][ks][slot=lg*16+row][j], 16B per slot. 8 KiB.
    __shared__ __attribute__((aligned(16))) __hip_bfloat16 hA[2][4][64][8];
    // gate matrix, n'-major rows: [s 0..15][col' 0..511 (+pad12)] fp32, 33.5 KiB
    __shared__ __attribute__((aligned(16))) float gbuf[16][524];

    // B-fragments: wave w owns cols' [w*64, w*64+64) = 4 nf x 4 ks
    bf16x8 bfr[4][4];
#pragma unroll
    for (int nf = 0; nf < 4; ++nf)
#pragma unroll
        for (int ks = 0; ks < 4; ++ks)
            bfr[nf][ks] = *reinterpret_cast<const bf16x8*>(
                Whh2 + (size_t)(w * 64 + nf * 16 + lr) * H_RNN + ks * 32 + lg * 8);

    // zero hA (both buffers; rows 4..15 stay zero forever)
    {
        uint32_t* hz = (uint32_t*)hA;
#pragma unroll
        for (int k = 0; k < 4; ++k) hz[tid * 4 + k] = 0u;
    }
    __syncthreads();

    const int tb = (blockIdx.x * BPB + s_u) * SEG - BURN;   // per-lane chain time base
    const int xoff0 = tb * 1024 + m_u * 8;                  // byte offset into xg2
    float c_st = 0.f;
    int p = 0;

    for (int i = 0; i < STEPS; ++i) {
        // prefetch this step's xg (consumed after MFMA+barrier ~ hides L2/L3 latency)
        int xoff = xoff0 + i * 1024;
        xoff = (xoff < 0) ? 0 : xoff;
        uint2 xraw = *reinterpret_cast<const uint2*>((const char*)xg2 + xoff);

        // A-fragments from LDS (all waves read same 4KB, conflict-free b128)
        bf16x8 afr[4];
#pragma unroll
        for (int ks = 0; ks < 4; ++ks)
            afr[ks] = *reinterpret_cast<const bf16x8*>(&hA[p][ks][l][0]);

        f32x4 acc[4];
#pragma unroll
        for (int nf = 0; nf < 4; ++nf) acc[nf] = (f32x4){0.f, 0.f, 0.f, 0.f};
#pragma unroll
        for (int nf = 0; nf < 4; ++nf)
#pragma unroll
            for (int ks = 0; ks < 4; ++ks)
                acc[nf] = __builtin_amdgcn_mfma_f32_16x16x32_bf16(
                    afr[ks], bfr[nf][ks], acc[nf], 0, 0, 0);

        // scatter D-frags: lane holds col'=w*64+nf*16+lr, rows lg*4+r
#pragma unroll
        for (int nf = 0; nf < 4; ++nf) {
            const int col = w * 64 + nf * 16 + lr;
#pragma unroll
            for (int r = 0; r < 4; ++r)
                gbuf[lg * 4 + r][col] = acc[nf][r];
        }
        __syncthreads();

        // update phase: lane owns (s_u, m_u); 4 gates = one b128
        float4 g4 = *reinterpret_cast<const float4*>(&gbuf[s_u][4 * m_u]);
        float x0 = __uint_as_float(xraw.x << 16);
        float x1 = __uint_as_float(xraw.x & 0xffff0000u);
        float x2 = __uint_as_float(xraw.y << 16);
        float x3 = __uint_as_float(xraw.y & 0xffff0000u);

        float I = fast_sigmoid(g4.x + x0);
        float F = fast_sigmoid(g4.y + x1);
        float G = fast_tanh  (g4.z + x2);
        float O = fast_sigmoid(g4.w + x3);
        float cn = F * c_st + I * G;
        const bool neg = (tb + i) < 0;          // chain not started yet
        c_st = neg ? 0.f : cn;
        float h = neg ? 0.f : O * fast_tanh(c_st);

        // write h (bf16) into next A-buffer
        hA[p ^ 1][m_u >> 5][((m_u >> 3) & 3) * 16 + s_u][m_u & 7] = __float2bfloat16(h);

        if (i >= BURN) {                        // block-uniform
            const int t = tb + i;
            float rv = fmaxf(h, 0.f);
            out[(size_t)t * OUT_COLS + 256 + m_u] = rv;
            out[((size_t)T_TOTAL + t) * OUT_COLS + 256 + m_u] = rv;
        }
        __syncthreads();
        p ^= 1;
    }
}

// ---------------- host ----------------

extern "C" void kernel_launch(void* const* d_in, const int* in_sizes, int n_in,
                              void* d_out, int out_size, void* d_ws, size_t ws_size,
                              hipStream_t stream) {
    const float* features = (const float*)d_in[0];
    const float* W1   = (const float*)d_in[1];
    const float* b1   = (const float*)d_in[2];
    const float* W2   = (const float*)d_in[3];
    const float* b2   = (const float*)d_in[4];
    const float* W_ih = (const float*)d_in[5];
    const float* b_ih = (const float*)d_in[6];
    const float* W_hh = (const float*)d_in[7];
    const float* b_hh = (const float*)d_in[8];
    float* out = (float*)d_out;

    char* ws = (char*)d_ws;
    __hip_bfloat16* xg2  = (__hip_bfloat16*)ws;                    // 32 MiB
    size_t off = (size_t)T_TOTAL * G4 * 2;
    __hip_bfloat16* Abf  = (__hip_bfloat16*)(ws + off); off += (size_t)T_TOTAL * KP1 * 2;
    __hip_bfloat16* W1bf = (__hip_bfloat16*)(ws + off); off += (size_t)H_FNN * KP1 * 2;
    __hip_bfloat16* W2bf = (__hip_bfloat16*)(ws + off); off += (size_t)D_FNN * H_FNN * 2;
    __hip_bfloat16* Whh2 = (__hip_bfloat16*)(ws + off);

    hipLaunchKernelGGL(cast_features, dim3(T_TOTAL * KP1 / 256), dim3(256), 0, stream, features, Abf);
    hipLaunchKernelGGL(cast_w1,       dim3(H_FNN * KP1 / 256),   dim3(256), 0, stream, W1, W1bf);
    hipLaunchKernelGGL(cast_w2,       dim3(D_FNN * H_FNN / 256), dim3(256), 0, stream, W2, W2bf);
    hipLaunchKernelGGL(cast_whh,      dim3(G4 * H_RNN / 256),    dim3(256), 0, stream, W_hh, Whh2);
    hipLaunchKernelGGL(xgates_kernel, dim3(T_TOTAL / 32), dim3(512), 0, stream,
                       features, W_ih, b_ih, b_hh, xg2);
    hipLaunchKernelGGL(fnn_mfma,      dim3(T_TOTAL / 64), dim3(512), 0, stream,
                       Abf, W1bf, b1, W2bf, b2, out);
    hipLaunchKernelGGL(lstm_mfma,     dim3(NBLK), dim3(512), 0, stream, xg2, Whh2, out);
}